// Round 2
// baseline (116.823 us; speedup 1.0000x reference)
//
#include <hip/hip_runtime.h>
#include <math.h>

// LinkedFocalLoss: mean_n [ w_n * (1-pt_n)^2 * ce_n ]
//   ce = -log_softmax(y_pred)[y_true], pt = exp(-ce), pred = argmax(y_pred)
//   w = 0.25 if (pred != gt && has_link[gt] && link_matrix[gt,pred]) else 1
// N=131072 rows, C=1000. HBM-bound: single 524 MB read of y_pred.
// Structure: 1 wave per row-group of 4, per-wave inline dtype detection,
// software-pipelined row loads, fused online-softmax butterfly reduce,
// per-wave partials + tiny deterministic final reduction. 2 launches total.

#define NROWS 131072
#define NC 1000
#define NF4 250                 // NC/4 float4 per row (4000 B, 16B aligned)
#define ROWS_PER_WAVE 4
#define WAVES_PER_BLOCK 4
#define ROWS_PER_BLOCK (ROWS_PER_WAVE * WAVES_PER_BLOCK)   // 16
#define NBLOCKS (NROWS / ROWS_PER_BLOCK)                   // 8192
#define NWAVES (NBLOCKS * WAVES_PER_BLOCK)                 // 32768
#define ALPHA_LINK 0.25f

__device__ __forceinline__ void load_row(const float4* __restrict__ rowp,
                                         int lane, float4 v[4]) {
    v[0] = rowp[lane];
    v[1] = rowp[lane + 64];
    v[2] = rowp[lane + 128];
    v[3] = (lane + 192 < NF4) ? rowp[lane + 192]
         : make_float4(-INFINITY, -INFINITY, -INFINITY, -INFINITY);
}

__global__ __launch_bounds__(256) void lfl_main(
    const float* __restrict__ yp,
    const int* __restrict__ yt,
    const unsigned char* __restrict__ linkb, const int* __restrict__ linki,
    const unsigned char* __restrict__ hasb,  const int* __restrict__ hasi,
    const unsigned int* __restrict__ hlw,
    float* __restrict__ partial)
{
    const int lane  = threadIdx.x & 63;
    const int wid   = threadIdx.x >> 6;
    const int gwave = blockIdx.x * WAVES_PER_BLOCK + wid;

    // ---- per-wave format detection (L2-hit loads + 2 ballots) ----
    // y_true int64?  hi-words (odd 32-bit words) of first 64 entries all zero.
    const int hi = yt[2 * lane + 1];
    const int y64 = (__ballot(hi != 0) == 0ULL);
    // link/has_link as packed bool bytes?  some word of has_link[0..249] > 1.
    const unsigned int h0 = hlw[lane];
    const unsigned int h1 = hlw[lane + 64];
    const unsigned int h2 = hlw[lane + 128];
    const unsigned int h3 = (lane + 192 < NF4) ? hlw[lane + 192] : 0u;
    const int bfmt = (__ballot((h0 > 1u) | (h1 > 1u) | (h2 > 1u) | (h3 > 1u)) != 0ULL);

    const int row0 = blockIdx.x * ROWS_PER_BLOCK + wid * ROWS_PER_WAVE;
    float wsum = 0.0f;

    // prefetch row 0
    float4 v[4];
    load_row((const float4*)(yp + (size_t)row0 * NC), lane, v);

    #pragma unroll
    for (int r = 0; r < ROWS_PER_WAVE; ++r) {
        const int row = row0 + r;
        const int target = y64 ? yt[2 * row] : yt[row];
        const int tf = target >> 2;   // float4 index holding the target logit
        const int tl = target & 3;

        // software-pipeline: issue next row's loads before this row's reduce
        float4 vn[4];
        if (r + 1 < ROWS_PER_WAVE)
            load_row((const float4*)(yp + (size_t)(row + 1) * NC), lane, vn);

        // ---- lane-local max + argmax (first occurrence) + target capture
        float m = -INFINITY;
        int   idx = 1 << 30;
        float xt = 0.0f;
        #pragma unroll
        for (int k = 0; k < 4; ++k) {
            const int f  = lane + 64 * k;
            const int c0 = f * 4;
            const float x0 = v[k].x, x1 = v[k].y, x2 = v[k].z, x3 = v[k].w;
            if (x0 > m) { m = x0; idx = c0; }
            if (x1 > m) { m = x1; idx = c0 + 1; }
            if (x2 > m) { m = x2; idx = c0 + 2; }
            if (x3 > m) { m = x3; idx = c0 + 3; }
            if (f == tf) xt = (tl == 0) ? x0 : (tl == 1) ? x1 : (tl == 2) ? x2 : x3;
        }

        // ---- lane-local exp-sum against lane-local max (padded -INF -> 0)
        float s = 0.0f;
        #pragma unroll
        for (int k = 0; k < 4; ++k) {
            s += __expf(v[k].x - m) + __expf(v[k].y - m)
               + __expf(v[k].z - m) + __expf(v[k].w - m);
        }

        // broadcast target logit (independent of butterfly chain)
        const float xts = __shfl(xt, tf & 63);

        // ---- fused online-softmax butterfly: merge (m, idx, s) in 6 steps
        #pragma unroll
        for (int off = 32; off; off >>= 1) {
            const float om = __shfl_xor(m, off);
            const int   oi = __shfl_xor(idx, off);
            const float os = __shfl_xor(s, off);
            const float mn = fmaxf(m, om);
            s = s * __expf(m - mn) + os * __expf(om - mn);
            if (om > m || (om == m && oi < idx)) idx = oi;   // tie -> lower index
            m = mn;
        }

        const float logp_t = xts - m - __logf(s);
        const float ce = -logp_t;
        const float pt = __expf(logp_t);
        const int pred = idx;

        const size_t ofs = (size_t)target * NC + (size_t)pred;
        const bool lm = bfmt ? (linkb[ofs] != 0)    : (linki[ofs] != 0);
        const bool hb = bfmt ? (hasb[target] != 0)  : (hasi[target] != 0);
        const float w = (lm && hb && (pred != target)) ? ALPHA_LINK : 1.0f;

        const float ompt = 1.0f - pt;
        wsum += w * ompt * ompt * ce;

        if (r + 1 < ROWS_PER_WAVE) {
            v[0] = vn[0]; v[1] = vn[1]; v[2] = vn[2]; v[3] = vn[3];
        }
    }

    if (lane == 0) partial[gwave] = wsum;
}

// ---- final deterministic reduction -----------------------------------------
__global__ __launch_bounds__(1024) void lfl_final(const float* __restrict__ partial,
                                                  float* __restrict__ out) {
    __shared__ float sm[1024];
    float s = 0.0f;
    for (int i = threadIdx.x; i < NWAVES; i += 1024) s += partial[i];
    sm[threadIdx.x] = s;
    __syncthreads();
    for (int stride = 512; stride; stride >>= 1) {
        if ((int)threadIdx.x < stride) sm[threadIdx.x] += sm[threadIdx.x + stride];
        __syncthreads();
    }
    if (threadIdx.x == 0) out[0] = sm[0] * (1.0f / (float)NROWS);
}

extern "C" void kernel_launch(void* const* d_in, const int* in_sizes, int n_in,
                              void* d_out, int out_size, void* d_ws, size_t ws_size,
                              hipStream_t stream) {
    const float* yp = (const float*)d_in[0];
    const int*   yt = (const int*)d_in[1];
    const void*  lk = d_in[2];
    const void*  hl = d_in[3];

    float* partial = (float*)d_ws;   // NWAVES floats (128 KB)

    lfl_main<<<NBLOCKS, 256, 0, stream>>>(
        yp, yt,
        (const unsigned char*)lk, (const int*)lk,
        (const unsigned char*)hl, (const int*)hl,
        (const unsigned int*)hl,
        partial);
    lfl_final<<<1, 1024, 0, stream>>>(partial, (float*)d_out);
}

// Round 4
// 103.418 us; speedup vs baseline: 1.1296x; 1.1296x over previous
//
#include <hip/hip_runtime.h>
#include <math.h>

// LinkedFocalLoss: mean_n [ w_n * (1-pt_n)^2 * ce_n ]
//   ce = -log_softmax(y_pred)[y_true], pt = exp(-ce), pred = argmax(y_pred)
//   w = 0.25 if (pred != gt && has_link[gt] && link_matrix[gt,pred]) else 1
// N=131072 rows, C=1000. HBM-bound: single 524 MB streaming read of y_pred.
// Round 4 (= round 3 fixed): nontemporal loads via clang ext_vector_type
// (HIP float4 is a struct, rejected by the builtin), pair-interleaved rows.

#define NROWS 131072
#define NC 1000
#define NF4 250                 // NC/4 float4 per row (4000 B, 16B aligned)
#define ROWS_PER_WAVE 4
#define WAVES_PER_BLOCK 4
#define ROWS_PER_BLOCK (ROWS_PER_WAVE * WAVES_PER_BLOCK)   // 16
#define NBLOCKS (NROWS / ROWS_PER_BLOCK)                   // 8192
#define NWAVES (NBLOCKS * WAVES_PER_BLOCK)                 // 32768
#define ALPHA_LINK 0.25f

typedef float floatx4 __attribute__((ext_vector_type(4)));

__device__ __forceinline__ void load_row_nt(const floatx4* __restrict__ rowp,
                                            int lane, floatx4 v[4]) {
    v[0] = __builtin_nontemporal_load(rowp + lane);
    v[1] = __builtin_nontemporal_load(rowp + lane + 64);
    v[2] = __builtin_nontemporal_load(rowp + lane + 128);
    if (lane + 192 < NF4) v[3] = __builtin_nontemporal_load(rowp + lane + 192);
    else                  v[3] = (floatx4){-INFINITY, -INFINITY, -INFINITY, -INFINITY};
}

// lane-local max/argmax/target-capture + expsum for one row held in v[4]
__device__ __forceinline__ void row_local(const floatx4 v[4], int lane, int tf, int tl,
                                          float& m, int& idx, float& xt, float& s) {
    m = -INFINITY; idx = 1 << 30; xt = 0.0f;
    #pragma unroll
    for (int k = 0; k < 4; ++k) {
        const int f  = lane + 64 * k;
        const int c0 = f * 4;
        const float x0 = v[k].x, x1 = v[k].y, x2 = v[k].z, x3 = v[k].w;
        if (x0 > m) { m = x0; idx = c0; }
        if (x1 > m) { m = x1; idx = c0 + 1; }
        if (x2 > m) { m = x2; idx = c0 + 2; }
        if (x3 > m) { m = x3; idx = c0 + 3; }
        if (f == tf) xt = (tl == 0) ? x0 : (tl == 1) ? x1 : (tl == 2) ? x2 : x3;
    }
    s = 0.0f;
    #pragma unroll
    for (int k = 0; k < 4; ++k) {
        s += __expf(v[k].x - m) + __expf(v[k].y - m)
           + __expf(v[k].z - m) + __expf(v[k].w - m);
    }
}

__global__ __launch_bounds__(256) void lfl_main(
    const float* __restrict__ yp,
    const int* __restrict__ yt,
    const unsigned char* __restrict__ linkb, const int* __restrict__ linki,
    const unsigned char* __restrict__ hasb,  const int* __restrict__ hasi,
    const unsigned int* __restrict__ hlw,
    float* __restrict__ partial)
{
    const int lane  = threadIdx.x & 63;
    const int wid   = threadIdx.x >> 6;
    const int gwave = blockIdx.x * WAVES_PER_BLOCK + wid;

    // ---- per-wave format detection (L2-hit loads + 2 ballots) ----
    const int hi = yt[2 * lane + 1];
    const int y64 = (__ballot(hi != 0) == 0ULL);
    const unsigned int h0 = hlw[lane];
    const unsigned int h1 = hlw[lane + 64];
    const unsigned int h2 = hlw[lane + 128];
    const unsigned int h3 = (lane + 192 < NF4) ? hlw[lane + 192] : 0u;
    const int bfmt = (__ballot((h0 > 1u) | (h1 > 1u) | (h2 > 1u) | (h3 > 1u)) != 0ULL);

    const int row0 = blockIdx.x * ROWS_PER_BLOCK + wid * ROWS_PER_WAVE;
    float wsum = 0.0f;

    #pragma unroll
    for (int p = 0; p < ROWS_PER_WAVE / 2; ++p) {
        const int rowA = row0 + 2 * p;
        const int rowB = rowA + 1;

        // issue all 8 loads back-to-back (2x MLP)
        floatx4 vA[4], vB[4];
        load_row_nt((const floatx4*)(yp + (size_t)rowA * NC), lane, vA);
        load_row_nt((const floatx4*)(yp + (size_t)rowB * NC), lane, vB);

        const int tgtA = y64 ? yt[2 * rowA] : yt[rowA];
        const int tgtB = y64 ? yt[2 * rowB] : yt[rowB];
        const int tfA = tgtA >> 2, tlA = tgtA & 3;
        const int tfB = tgtB >> 2, tlB = tgtB & 3;

        // two independent lane-local phases (ILP-2)
        float mA, xtA, sA, mB, xtB, sB;
        int idxA, idxB;
        row_local(vA, lane, tfA, tlA, mA, idxA, xtA, sA);
        row_local(vB, lane, tfB, tlB, mB, idxB, xtB, sB);

        const float xtsA = __shfl(xtA, tfA & 63);
        const float xtsB = __shfl(xtB, tfB & 63);

        // two interleaved online-softmax butterflies (independent chains)
        #pragma unroll
        for (int off = 32; off; off >>= 1) {
            const float omA = __shfl_xor(mA, off);
            const float omB = __shfl_xor(mB, off);
            const int   oiA = __shfl_xor(idxA, off);
            const int   oiB = __shfl_xor(idxB, off);
            const float osA = __shfl_xor(sA, off);
            const float osB = __shfl_xor(sB, off);
            const float mnA = fmaxf(mA, omA);
            const float mnB = fmaxf(mB, omB);
            sA = sA * __expf(mA - mnA) + osA * __expf(omA - mnA);
            sB = sB * __expf(mB - mnB) + osB * __expf(omB - mnB);
            if (omA > mA || (omA == mA && oiA < idxA)) idxA = oiA;
            if (omB > mB || (omB == mB && oiB < idxB)) idxB = oiB;
            mA = mnA; mB = mnB;
        }

        // finish both rows
        #pragma unroll
        for (int q = 0; q < 2; ++q) {
            const int   target = q ? tgtB : tgtA;
            const int   pred   = q ? idxB : idxA;
            const float logp_t = (q ? xtsB : xtsA) - (q ? mB : mA) - __logf(q ? sB : sA);
            const float ce = -logp_t;
            const float pt = __expf(logp_t);
            const size_t ofs = (size_t)target * NC + (size_t)pred;
            const bool lm = bfmt ? (linkb[ofs] != 0)   : (linki[ofs] != 0);
            const bool hb = bfmt ? (hasb[target] != 0) : (hasi[target] != 0);
            const float w = (lm && hb && (pred != target)) ? ALPHA_LINK : 1.0f;
            const float ompt = 1.0f - pt;
            wsum += w * ompt * ompt * ce;
        }
    }

    if (lane == 0) partial[gwave] = wsum;
}

// ---- final deterministic reduction -----------------------------------------
__global__ __launch_bounds__(1024) void lfl_final(const float* __restrict__ partial,
                                                  float* __restrict__ out) {
    __shared__ float sm[1024];
    float s = 0.0f;
    for (int i = threadIdx.x; i < NWAVES; i += 1024) s += partial[i];
    sm[threadIdx.x] = s;
    __syncthreads();
    for (int stride = 512; stride; stride >>= 1) {
        if ((int)threadIdx.x < stride) sm[threadIdx.x] += sm[threadIdx.x + stride];
        __syncthreads();
    }
    if (threadIdx.x == 0) out[0] = sm[0] * (1.0f / (float)NROWS);
}

extern "C" void kernel_launch(void* const* d_in, const int* in_sizes, int n_in,
                              void* d_out, int out_size, void* d_ws, size_t ws_size,
                              hipStream_t stream) {
    const float* yp = (const float*)d_in[0];
    const int*   yt = (const int*)d_in[1];
    const void*  lk = d_in[2];
    const void*  hl = d_in[3];

    float* partial = (float*)d_ws;   // NWAVES floats (128 KB)

    lfl_main<<<NBLOCKS, 256, 0, stream>>>(
        yp, yt,
        (const unsigned char*)lk, (const int*)lk,
        (const unsigned char*)hl, (const int*)hl,
        (const unsigned int*)hl,
        partial);
    lfl_final<<<1, 1024, 0, stream>>>(partial, (float*)d_out);
}

// Round 5
// 102.170 us; speedup vs baseline: 1.1434x; 1.0122x over previous
//
#include <hip/hip_runtime.h>
#include <math.h>

// LinkedFocalLoss: mean_n [ w_n * (1-pt_n)^2 * ce_n ]
//   ce = -log_softmax(y_pred)[y_true], pt = exp(-ce), pred = argmax(y_pred)
//   w = 0.25 if (pred != gt && has_link[gt] && link_matrix[gt,pred]) else 1
// N=131072 rows, C=1000. HBM-bound: single 524 MB streaming read of y_pred.
// Round 5: straight-line wave body — all 4 rows' loads (16 KB/wave) issued
// up front (nt, ext_vector float4), 4 interleaved online-softmax butterflies,
// de-serialized dtype detection. 2 launches.

#define NROWS 131072
#define NC 1000
#define NF4 250                 // NC/4 float4 per row (4000 B, 16B aligned)
#define ROWS_PER_WAVE 4
#define WAVES_PER_BLOCK 4
#define ROWS_PER_BLOCK (ROWS_PER_WAVE * WAVES_PER_BLOCK)   // 16
#define NBLOCKS (NROWS / ROWS_PER_BLOCK)                   // 8192
#define NWAVES (NBLOCKS * WAVES_PER_BLOCK)                 // 32768
#define ALPHA_LINK 0.25f

typedef float floatx4 __attribute__((ext_vector_type(4)));

__global__ __launch_bounds__(256, 4) void lfl_main(
    const float* __restrict__ yp,
    const int* __restrict__ yt,
    const unsigned char* __restrict__ linkb, const int* __restrict__ linki,
    const unsigned char* __restrict__ hasb,  const int* __restrict__ hasi,
    const unsigned int* __restrict__ hlw,
    float* __restrict__ partial)
{
    const int lane  = threadIdx.x & 63;
    const int wid   = threadIdx.x >> 6;
    const int gwave = blockIdx.x * WAVES_PER_BLOCK + wid;
    const int row0  = blockIdx.x * ROWS_PER_BLOCK + wid * ROWS_PER_WAVE;

    // ---- issue small (L2-hot) loads first: detect probes + both target
    //      candidates per row (select after ballot; removes serialization)
    const int det_hi = yt[2 * lane + 1];
    const unsigned int h0 = hlw[lane];
    const unsigned int h1 = hlw[lane + 64];
    const unsigned int h2 = hlw[lane + 128];
    const unsigned int h3 = (lane + 192 < NF4) ? hlw[lane + 192] : 0u;
    int t32[ROWS_PER_WAVE], t64[ROWS_PER_WAVE];
    #pragma unroll
    for (int r = 0; r < ROWS_PER_WAVE; ++r) {
        t32[r] = yt[row0 + r];
        t64[r] = yt[2 * (row0 + r)];
    }

    // ---- issue ALL 16 nontemporal row loads back-to-back (16 KB in flight)
    floatx4 v[ROWS_PER_WAVE][4];
    #pragma unroll
    for (int r = 0; r < ROWS_PER_WAVE; ++r) {
        const floatx4* rowp = (const floatx4*)(yp + (size_t)(row0 + r) * NC);
        v[r][0] = __builtin_nontemporal_load(rowp + lane);
        v[r][1] = __builtin_nontemporal_load(rowp + lane + 64);
        v[r][2] = __builtin_nontemporal_load(rowp + lane + 128);
        if (lane + 192 < NF4) v[r][3] = __builtin_nontemporal_load(rowp + lane + 192);
        else v[r][3] = (floatx4){-INFINITY, -INFINITY, -INFINITY, -INFINITY};
    }

    // ---- format ballots
    const int y64  = (__ballot(det_hi != 0) == 0ULL);
    const int bfmt = (__ballot((h0 > 1u) | (h1 > 1u) | (h2 > 1u) | (h3 > 1u)) != 0ULL);

    int tgt[ROWS_PER_WAVE], tf[ROWS_PER_WAVE], tl[ROWS_PER_WAVE];
    #pragma unroll
    for (int r = 0; r < ROWS_PER_WAVE; ++r) {
        tgt[r] = y64 ? t64[r] : t32[r];
        tf[r] = tgt[r] >> 2;
        tl[r] = tgt[r] & 3;
    }

    // ---- lane-local max/argmax/target-capture + expsum, per row
    float m[ROWS_PER_WAVE], xt[ROWS_PER_WAVE], s[ROWS_PER_WAVE];
    int idx[ROWS_PER_WAVE];
    #pragma unroll
    for (int r = 0; r < ROWS_PER_WAVE; ++r) {
        float mm = -INFINITY; int ii = 1 << 30; float xx = 0.0f;
        #pragma unroll
        for (int k = 0; k < 4; ++k) {
            const int f  = lane + 64 * k;
            const int c0 = f * 4;
            const float x0 = v[r][k].x, x1 = v[r][k].y, x2 = v[r][k].z, x3 = v[r][k].w;
            if (x0 > mm) { mm = x0; ii = c0; }
            if (x1 > mm) { mm = x1; ii = c0 + 1; }
            if (x2 > mm) { mm = x2; ii = c0 + 2; }
            if (x3 > mm) { mm = x3; ii = c0 + 3; }
            if (f == tf[r]) xx = (tl[r] == 0) ? x0 : (tl[r] == 1) ? x1 : (tl[r] == 2) ? x2 : x3;
        }
        float ss = 0.0f;
        #pragma unroll
        for (int k = 0; k < 4; ++k) {
            ss += __expf(v[r][k].x - mm) + __expf(v[r][k].y - mm)
                + __expf(v[r][k].z - mm) + __expf(v[r][k].w - mm);
        }
        m[r] = mm; idx[r] = ii; xt[r] = xx; s[r] = ss;
    }

    // ---- broadcast target logits
    float xts[ROWS_PER_WAVE];
    #pragma unroll
    for (int r = 0; r < ROWS_PER_WAVE; ++r) xts[r] = __shfl(xt[r], tf[r] & 63);

    // ---- 4 interleaved online-softmax butterflies (independent chains)
    #pragma unroll
    for (int off = 32; off; off >>= 1) {
        #pragma unroll
        for (int r = 0; r < ROWS_PER_WAVE; ++r) {
            const float om = __shfl_xor(m[r], off);
            const int   oi = __shfl_xor(idx[r], off);
            const float os = __shfl_xor(s[r], off);
            const float mn = fmaxf(m[r], om);
            s[r] = s[r] * __expf(m[r] - mn) + os * __expf(om - mn);
            if (om > m[r] || (om == m[r] && oi < idx[r])) idx[r] = oi;   // tie -> lower idx
            m[r] = mn;
        }
    }

    // ---- finish rows
    float wsum = 0.0f;
    #pragma unroll
    for (int r = 0; r < ROWS_PER_WAVE; ++r) {
        const float logp_t = xts[r] - m[r] - __logf(s[r]);
        const float ce = -logp_t;
        const float pt = __expf(logp_t);
        const int pred = idx[r];
        const size_t ofs = (size_t)tgt[r] * NC + (size_t)pred;
        const bool lm = bfmt ? (linkb[ofs] != 0)    : (linki[ofs] != 0);
        const bool hb = bfmt ? (hasb[tgt[r]] != 0)  : (hasi[tgt[r]] != 0);
        const float w = (lm && hb && (pred != tgt[r])) ? ALPHA_LINK : 1.0f;
        const float ompt = 1.0f - pt;
        wsum += w * ompt * ompt * ce;
    }

    if (lane == 0) partial[gwave] = wsum;
}

// ---- final deterministic reduction -----------------------------------------
__global__ __launch_bounds__(1024) void lfl_final(const float* __restrict__ partial,
                                                  float* __restrict__ out) {
    __shared__ float sm[1024];
    float s = 0.0f;
    for (int i = threadIdx.x; i < NWAVES; i += 1024) s += partial[i];
    sm[threadIdx.x] = s;
    __syncthreads();
    for (int stride = 512; stride; stride >>= 1) {
        if ((int)threadIdx.x < stride) sm[threadIdx.x] += sm[threadIdx.x + stride];
        __syncthreads();
    }
    if (threadIdx.x == 0) out[0] = sm[0] * (1.0f / (float)NROWS);
}

extern "C" void kernel_launch(void* const* d_in, const int* in_sizes, int n_in,
                              void* d_out, int out_size, void* d_ws, size_t ws_size,
                              hipStream_t stream) {
    const float* yp = (const float*)d_in[0];
    const int*   yt = (const int*)d_in[1];
    const void*  lk = d_in[2];
    const void*  hl = d_in[3];

    float* partial = (float*)d_ws;   // NWAVES floats (128 KB)

    lfl_main<<<NBLOCKS, 256, 0, stream>>>(
        yp, yt,
        (const unsigned char*)lk, (const int*)lk,
        (const unsigned char*)hl, (const int*)hl,
        (const unsigned int*)hl,
        partial);
    lfl_final<<<1, 1024, 0, stream>>>(partial, (float*)d_out);
}